// Round 2
// baseline (1186.244 us; speedup 1.0000x reference)
//
#include <hip/hip_runtime.h>

typedef __attribute__((ext_vector_type(8))) short short8;
typedef __attribute__((ext_vector_type(4))) float f32x4;

static constexpr int CHUNK_E = 512;   // edges per wave in spmm

__device__ __forceinline__ float bf2f(unsigned short u){
  return __uint_as_float(((unsigned int)u) << 16);
}
__device__ __forceinline__ unsigned short f2bf(float f){
  unsigned int u = __float_as_uint(f);
  u += 0x7fffu + ((u >> 16) & 1u);   // RNE; NaN not expected in this workload
  return (unsigned short)(u >> 16);
}
// dtype-dispatching scalar load: isF32 ? f32[i] : bf16[i]
__device__ __forceinline__ float ldf(const void* p, long i, int isF32){
  return isF32 ? ((const float*)p)[i] : bf2f(((const unsigned short*)p)[i]);
}

// ---- detect input dtype: bf16 (flag=0) vs f32 (flag=1) ----
// Even-index u16s of x: real bf16 values (exp <= ~0x82 for N(0,1)) if bf16;
// random mantissa halves (uniform exponent field, ~6% >= 0xF0) if f32.
__global__ void detect(const unsigned short* __restrict__ x, int* __restrict__ flag){
  __shared__ int s;
  if (threadIdx.x == 0) s = 0;
  __syncthreads();
  int bad = 0;
  for (int i = threadIdx.x; i < 2048; i += 256){
    unsigned int e = ((unsigned int)x[2 * i] >> 7) & 0xffu;
    if (e >= 0xF0u) bad = 1;
  }
  if (bad) atomicOr(&s, 1);
  __syncthreads();
  if (threadIdx.x == 0) *flag = s;
}

// ---- transpose W [K][128] -> WT [128][K], output canonical bf16 ----
__global__ void wtrans(const void* __restrict__ W, unsigned short* __restrict__ WT,
                       int K, const int* __restrict__ flag){
  int isF32 = *flag;
  int idx = blockIdx.x * 256 + threadIdx.x;
  if (idx >= K * 128) return;
  int n = idx / K, k = idx - n * K;
  WT[idx] = f2bf(ldf(W, (long)k * 128 + n, isF32));
}

// ---- out[M][128] = A[M][K] @ W[K][128] (+bias), canonical bf16 out ----
// A dtype: (aFollowsFlag && *flag) ? f32 : bf16. Bias dtype follows flag.
// block: 256 thr = 4 waves; block tile M=128, wave tile M=32, N=128,
// K staged in LDS 128 at a time (+8-short pad -> only 2-way bank aliasing).
template<int K>
__global__ __launch_bounds__(256) void gemm_bf16(
    const void* __restrict__ A,
    const unsigned short* __restrict__ WT,   // [128][K] bf16 (n-major)
    const void* __restrict__ bias,           // [128] or nullptr
    unsigned short* __restrict__ out,        // [M][128] bf16
    int M, const int* __restrict__ flagp, int aFollowsFlag)
{
  constexpr int KB = 128;
  constexpr int KP = KB + 8;
  __shared__ __align__(16) unsigned short lW[128 * KP];

  const int fl   = *flagp;
  const int aF32 = aFollowsFlag ? fl : 0;
  const int tid  = threadIdx.x;
  const int lane = tid & 63;
  const int wav  = tid >> 6;
  const int l16  = lane & 15;
  const int quad = lane >> 4;
  const int rowBase = blockIdx.x * 128 + wav * 32;

  f32x4 acc[2][8];
#pragma unroll
  for (int s = 0; s < 2; ++s)
#pragma unroll
    for (int nt = 0; nt < 8; ++nt) acc[s][nt] = (f32x4){0.f, 0.f, 0.f, 0.f};

  for (int kb = 0; kb < K; kb += KB){
    __syncthreads();
#pragma unroll
    for (int i = tid; i < 128 * KB / 8; i += 256){
      int n = i >> 4;     // i / (KB/8), KB=128
      int c = i & 15;
      *(short8*)&lW[n * KP + c * 8] = *(const short8*)&WT[n * K + kb + c * 8];
    }
    __syncthreads();
#pragma unroll
    for (int k0 = 0; k0 < KB; k0 += 32){
      short8 aF[2];
#pragma unroll
      for (int s = 0; s < 2; ++s){
        int r = rowBase + s * 16 + l16;
        short8 v = {};
        if (r < M){
          long off = (long)r * K + kb + k0 + quad * 8;
          if (aF32){
            const float* Af = (const float*)A + off;
            f32x4 p0 = *(const f32x4*)Af;
            f32x4 p1 = *(const f32x4*)(Af + 4);
            v[0] = (short)f2bf(p0[0]); v[1] = (short)f2bf(p0[1]);
            v[2] = (short)f2bf(p0[2]); v[3] = (short)f2bf(p0[3]);
            v[4] = (short)f2bf(p1[0]); v[5] = (short)f2bf(p1[1]);
            v[6] = (short)f2bf(p1[2]); v[7] = (short)f2bf(p1[3]);
          } else {
            v = *(const short8*)((const unsigned short*)A + off);
          }
        }
        aF[s] = v;
      }
#pragma unroll
      for (int nt = 0; nt < 8; ++nt){
        short8 bF = *(const short8*)&lW[(nt * 16 + l16) * KP + k0 + quad * 8];
        acc[0][nt] = __builtin_amdgcn_mfma_f32_16x16x32_bf16(aF[0], bF, acc[0][nt], 0, 0, 0);
        acc[1][nt] = __builtin_amdgcn_mfma_f32_16x16x32_bf16(aF[1], bF, acc[1][nt], 0, 0, 0);
      }
    }
  }

#pragma unroll
  for (int s = 0; s < 2; ++s){
    int r0 = rowBase + s * 16 + quad * 4;
#pragma unroll
    for (int nt = 0; nt < 8; ++nt){
      int col = nt * 16 + l16;
      float bv = bias ? ldf(bias, col, fl) : 0.0f;
#pragma unroll
      for (int rg = 0; rg < 4; ++rg){
        int r = r0 + rg;
        if (r < M) out[(long)r * 128 + col] = f2bf(acc[s][nt][rg] + bv);
      }
    }
  }
}

// ---- acc[r] += val[e] * Y[col[e]]  (rows sorted; register acc + atomic flush)
// one wave per 512-edge chunk; lane owns features {2*lane, 2*lane+1}
__global__ __launch_bounds__(256) void spmm(
    const int* __restrict__ rows, const int* __restrict__ cols,
    const void* __restrict__ vals,
    const unsigned short* __restrict__ Y,   // [N][128] bf16
    float* __restrict__ acc,                // [N][128] f32, pre-zeroed
    int E, int nchunks, const int* __restrict__ flagp)
{
  const int fl   = *flagp;
  const int lane = threadIdx.x & 63;
  const int wav  = threadIdx.x >> 6;
  int c = blockIdx.x * 4 + wav;
  if (c >= nchunks) return;
  int e  = c * CHUNK_E;
  int e1 = min(e + CHUNK_E, E);
  float ax = 0.f, ay = 0.f;
  int cur = rows[e];
  for (; e < e1; ++e){
    int r = rows[e];
    if (r != cur){
      atomicAdd(&acc[(long)cur * 128 + 2 * lane],     ax);
      atomicAdd(&acc[(long)cur * 128 + 2 * lane + 1], ay);
      ax = 0.f; ay = 0.f; cur = r;
    }
    float v = ldf(vals, e, fl);
    unsigned int yy = *(const unsigned int*)&Y[(long)cols[e] * 128 + 2 * lane];
    ax = fmaf(v, bf2f((unsigned short)(yy & 0xffffu)), ax);
    ay = fmaf(v, bf2f((unsigned short)(yy >> 16)),     ay);
  }
  atomicAdd(&acc[(long)cur * 128 + 2 * lane],     ax);
  atomicAdd(&acc[(long)cur * 128 + 2 * lane + 1], ay);
}

// ---- x1 = relu(acc1 + b1) + z ----
__global__ __launch_bounds__(256) void ew_x1(
    const float* __restrict__ acc1, const unsigned short* __restrict__ z,
    const void* __restrict__ b1, unsigned short* __restrict__ x1,
    int total4, const int* __restrict__ flagp)
{
  const int fl = *flagp;
  int idx = blockIdx.x * 256 + threadIdx.x;
  if (idx >= total4) return;
  float4 a = ((const float4*)acc1)[idx];
  uint2 zz = *(const uint2*)&z[idx * 4];
  int c0 = (idx & 31) * 4;
  float b0 = ldf(b1, c0, fl),     bb1 = ldf(b1, c0 + 1, fl);
  float b2v = ldf(b1, c0 + 2, fl), b3 = ldf(b1, c0 + 3, fl);
  float r0 = fmaxf(a.x + b0,  0.f) + bf2f((unsigned short)(zz.x & 0xffffu));
  float r1 = fmaxf(a.y + bb1, 0.f) + bf2f((unsigned short)(zz.x >> 16));
  float r2 = fmaxf(a.z + b2v, 0.f) + bf2f((unsigned short)(zz.y & 0xffffu));
  float r3 = fmaxf(a.w + b3,  0.f) + bf2f((unsigned short)(zz.y >> 16));
  uint2 o;
  o.x = (unsigned int)f2bf(r0) | ((unsigned int)f2bf(r1) << 16);
  o.y = (unsigned int)f2bf(r2) | ((unsigned int)f2bf(r3) << 16);
  *(uint2*)&x1[idx * 4] = o;
}

// ---- out = log_softmax(h + b2) per row of 128; one wave per row ----
// output dtype follows flag (f32 or bf16)
__global__ __launch_bounds__(256) void lsm(
    const float* __restrict__ h, const void* __restrict__ b2,
    void* __restrict__ out, int N, const int* __restrict__ flagp)
{
  const int fl   = *flagp;
  const int lane = threadIdx.x & 63;
  const int wav  = threadIdx.x >> 6;
  long row = (long)blockIdx.x * 4 + wav;
  if (row >= N) return;
  float v0 = h[row * 128 + lane]      + ldf(b2, lane, fl);
  float v1 = h[row * 128 + 64 + lane] + ldf(b2, 64 + lane, fl);
  float m = fmaxf(v0, v1);
#pragma unroll
  for (int off = 32; off; off >>= 1) m = fmaxf(m, __shfl_xor(m, off));
  float s = expf(v0 - m) + expf(v1 - m);
#pragma unroll
  for (int off = 32; off; off >>= 1) s += __shfl_xor(s, off);
  float lse = m + logf(s);
  if (fl){
    ((float*)out)[row * 128 + lane]      = v0 - lse;
    ((float*)out)[row * 128 + 64 + lane] = v1 - lse;
  } else {
    ((unsigned short*)out)[row * 128 + lane]      = f2bf(v0 - lse);
    ((unsigned short*)out)[row * 128 + 64 + lane] = f2bf(v1 - lse);
  }
}

extern "C" void kernel_launch(void* const* d_in, const int* in_sizes, int n_in,
                              void* d_out, int out_size, void* d_ws, size_t ws_size,
                              hipStream_t stream)
{
  const void* x    = d_in[0];
  const int*  erow = (const int*)d_in[1];
  const int*  ecol = (const int*)d_in[2];
  const void* eval = d_in[3];
  const void* Wres = d_in[4];
  const void* bres = d_in[5];
  const void* W1   = d_in[6];
  const void* b1   = d_in[7];
  const void* W2   = d_in[8];
  const void* b2   = d_in[9];
  const int N = in_sizes[0] / 256;   // 100000
  const int E = in_sizes[1];         // 1600000

  char* ws = (char*)d_ws;
  size_t szB = (size_t)N * 128 * 2;  // one bf16 [N,128] plane (25.6 MB)
  size_t szF = (size_t)N * 128 * 4;  // one f32  [N,128] plane (51.2 MB)
  unsigned short* bufA  = (unsigned short*)ws;          // y1, then x1 (bf16)
  float*          bufB  = (float*)(ws + szB);           // f32 spmm accumulator
  unsigned short* WresT = (unsigned short*)(ws + szB + szF);
  unsigned short* W1T   = WresT + 256 * 128;
  unsigned short* W2T   = W1T   + 256 * 128;
  int*            flag  = (int*)(W2T + 256 * 128);
  // z and y2 (bf16, 25.6 MB) live in d_out: fits whether d_out is bf16 or f32.
  unsigned short* zbuf  = (unsigned short*)d_out;

  detect<<<1, 256, 0, stream>>>((const unsigned short*)x, flag);
  wtrans<<<128, 256, 0, stream>>>(Wres, WresT, 256, flag);
  wtrans<<<128, 256, 0, stream>>>(W1,   W1T,   256, flag);
  wtrans<<< 64, 256, 0, stream>>>(W2,   W2T,   128, flag);
  hipMemsetAsync(bufB, 0, szF, stream);

  const int gBlocks = (N + 127) / 128;
  gemm_bf16<256><<<gBlocks, 256, 0, stream>>>(x, WresT, bres, zbuf, N, flag, 1);   // z
  gemm_bf16<256><<<gBlocks, 256, 0, stream>>>(x, W1T, nullptr, bufA, N, flag, 1);  // y1

  const int nchunks = (E + CHUNK_E - 1) / CHUNK_E;
  const int sBlocks = (nchunks + 3) / 4;
  spmm<<<sBlocks, 256, 0, stream>>>(erow, ecol, eval, bufA, bufB, E, nchunks, flag); // acc1

  const int total4 = N * 128 / 4;
  ew_x1<<<(total4 + 255) / 256, 256, 0, stream>>>(bufB, zbuf, b1, bufA, total4, flag); // x1

  gemm_bf16<128><<<gBlocks, 256, 0, stream>>>(bufA, W2T, nullptr, zbuf, N, flag, 0);  // y2

  hipMemsetAsync(bufB, 0, szF, stream);
  spmm<<<sBlocks, 256, 0, stream>>>(erow, ecol, eval, zbuf, bufB, E, nchunks, flag);  // acc2

  lsm<<<(N + 3) / 4, 256, 0, stream>>>(bufB, b2, d_out, N, flag);
}

// Round 3
// 481.863 us; speedup vs baseline: 2.4618x; 2.4618x over previous
//
#include <hip/hip_runtime.h>

typedef __attribute__((ext_vector_type(8))) short short8;
typedef __attribute__((ext_vector_type(4))) float f32x4;

__device__ __forceinline__ float bf2f(unsigned short u){
  return __uint_as_float(((unsigned int)u) << 16);
}
__device__ __forceinline__ unsigned short f2bf(float f){
  unsigned int u = __float_as_uint(f);
  u += 0x7fffu + ((u >> 16) & 1u);   // RNE
  return (unsigned short)(u >> 16);
}
// dtype-dispatching scalar load: isF32 ? f32[i] : bf16[i]
__device__ __forceinline__ float ldf(const void* p, long i, int isF32){
  return isF32 ? ((const float*)p)[i] : bf2f(((const unsigned short*)p)[i]);
}

// ---- detect input dtype: bf16 (flag=0) vs f32 (flag=1) ----
__global__ void detect(const unsigned short* __restrict__ x, int* __restrict__ flag){
  __shared__ int s;
  if (threadIdx.x == 0) s = 0;
  __syncthreads();
  int bad = 0;
  for (int i = threadIdx.x; i < 2048; i += 256){
    unsigned int e = ((unsigned int)x[2 * i] >> 7) & 0xffu;
    if (e >= 0xF0u) bad = 1;
  }
  if (bad) atomicOr(&s, 1);
  __syncthreads();
  if (threadIdx.x == 0) *flag = s;
}

// ---- transpose W [K][128] -> WT [128][K], output canonical bf16 ----
__global__ void wtrans(const void* __restrict__ W, unsigned short* __restrict__ WT,
                       int K, const int* __restrict__ flag){
  int isF32 = *flag;
  int idx = blockIdx.x * 256 + threadIdx.x;
  if (idx >= K * 128) return;
  int n = idx / K, k = idx - n * K;
  WT[idx] = f2bf(ldf(W, (long)k * 128 + n, isF32));
}

// ---- row_ptr from sorted rows: rs[r] = first edge with row >= r ----
__global__ void rowptr_k(const int* __restrict__ rows, int* __restrict__ rs,
                         int E, int N){
  int e = blockIdx.x * 256 + threadIdx.x;
  if (e >= E) return;
  if (e == 0){
    for (int r = 0; r <= rows[0]; ++r) rs[r] = 0;
  } else {
    int a = rows[e - 1], b = rows[e];
    for (int r = a + 1; r <= b; ++r) rs[r] = e;
  }
  if (e == E - 1){
    for (int r = rows[E - 1] + 1; r <= N; ++r) rs[r] = E;
  }
}

// ---- out[M][128] = A[M][K] @ W[K][128] (+bias), canonical bf16 out ----
template<int K>
__global__ __launch_bounds__(256) void gemm_bf16(
    const void* __restrict__ A,
    const unsigned short* __restrict__ WT,   // [128][K] bf16 (n-major)
    const void* __restrict__ bias,           // [128] or nullptr
    unsigned short* __restrict__ out,        // [M][128] bf16
    int M, const int* __restrict__ flagp, int aFollowsFlag)
{
  constexpr int KB = 128;
  constexpr int KP = KB + 8;
  __shared__ __align__(16) unsigned short lW[128 * KP];

  const int fl   = *flagp;
  const int aF32 = aFollowsFlag ? fl : 0;
  const int tid  = threadIdx.x;
  const int lane = tid & 63;
  const int wav  = tid >> 6;
  const int l16  = lane & 15;
  const int quad = lane >> 4;
  const int rowBase = blockIdx.x * 128 + wav * 32;

  f32x4 acc[2][8];
#pragma unroll
  for (int s = 0; s < 2; ++s)
#pragma unroll
    for (int nt = 0; nt < 8; ++nt) acc[s][nt] = (f32x4){0.f, 0.f, 0.f, 0.f};

  for (int kb = 0; kb < K; kb += KB){
    __syncthreads();
#pragma unroll
    for (int i = tid; i < 128 * KB / 8; i += 256){
      int n = i >> 4;
      int c = i & 15;
      *(short8*)&lW[n * KP + c * 8] = *(const short8*)&WT[n * K + kb + c * 8];
    }
    __syncthreads();
#pragma unroll
    for (int k0 = 0; k0 < KB; k0 += 32){
      short8 aF[2];
#pragma unroll
      for (int s = 0; s < 2; ++s){
        int r = rowBase + s * 16 + l16;
        short8 v = {};
        if (r < M){
          long off = (long)r * K + kb + k0 + quad * 8;
          if (aF32){
            const float* Af = (const float*)A + off;
            f32x4 p0 = *(const f32x4*)Af;
            f32x4 p1 = *(const f32x4*)(Af + 4);
            v[0] = (short)f2bf(p0[0]); v[1] = (short)f2bf(p0[1]);
            v[2] = (short)f2bf(p0[2]); v[3] = (short)f2bf(p0[3]);
            v[4] = (short)f2bf(p1[0]); v[5] = (short)f2bf(p1[1]);
            v[6] = (short)f2bf(p1[2]); v[7] = (short)f2bf(p1[3]);
          } else {
            v = *(const short8*)((const unsigned short*)A + off);
          }
        }
        aF[s] = v;
      }
#pragma unroll
      for (int nt = 0; nt < 8; ++nt){
        short8 bF = *(const short8*)&lW[(nt * 16 + l16) * KP + k0 + quad * 8];
        acc[0][nt] = __builtin_amdgcn_mfma_f32_16x16x32_bf16(aF[0], bF, acc[0][nt], 0, 0, 0);
        acc[1][nt] = __builtin_amdgcn_mfma_f32_16x16x32_bf16(aF[1], bF, acc[1][nt], 0, 0, 0);
      }
    }
  }

#pragma unroll
  for (int s = 0; s < 2; ++s){
    int r0 = rowBase + s * 16 + quad * 4;
#pragma unroll
    for (int nt = 0; nt < 8; ++nt){
      int col = nt * 16 + l16;
      float bv = bias ? ldf(bias, col, fl) : 0.0f;
#pragma unroll
      for (int rg = 0; rg < 4; ++rg){
        int r = r0 + rg;
        if (r < M) out[(long)r * 128 + col] = f2bf(acc[s][nt][rg] + bv);
      }
    }
  }
}

// ---- row-parallel gather accumulate: 2 feats/lane over row edges ----
// e bounds made wave-uniform via readfirstlane -> cols/vals scalar loads.
__device__ __forceinline__ void row_gather(
    int e0, int e1, const int* __restrict__ cols, const void* __restrict__ vals,
    const unsigned short* __restrict__ Y, int lane, int fl,
    float& outx, float& outy)
{
  float ax0 = 0.f, ay0 = 0.f, ax1 = 0.f, ay1 = 0.f;
  int e = e0;
  for (; e + 4 <= e1; e += 4){
    int c0 = cols[e], c1 = cols[e + 1], c2 = cols[e + 2], c3 = cols[e + 3];
    float v0 = ldf(vals, e, fl),     v1 = ldf(vals, e + 1, fl);
    float v2 = ldf(vals, e + 2, fl), v3 = ldf(vals, e + 3, fl);
    unsigned int q0 = *(const unsigned int*)&Y[(long)c0 * 128 + 2 * lane];
    unsigned int q1 = *(const unsigned int*)&Y[(long)c1 * 128 + 2 * lane];
    unsigned int q2 = *(const unsigned int*)&Y[(long)c2 * 128 + 2 * lane];
    unsigned int q3 = *(const unsigned int*)&Y[(long)c3 * 128 + 2 * lane];
    ax0 = fmaf(v0, bf2f((unsigned short)(q0 & 0xffffu)), ax0);
    ay0 = fmaf(v0, bf2f((unsigned short)(q0 >> 16)),     ay0);
    ax1 = fmaf(v1, bf2f((unsigned short)(q1 & 0xffffu)), ax1);
    ay1 = fmaf(v1, bf2f((unsigned short)(q1 >> 16)),     ay1);
    ax0 = fmaf(v2, bf2f((unsigned short)(q2 & 0xffffu)), ax0);
    ay0 = fmaf(v2, bf2f((unsigned short)(q2 >> 16)),     ay0);
    ax1 = fmaf(v3, bf2f((unsigned short)(q3 & 0xffffu)), ax1);
    ay1 = fmaf(v3, bf2f((unsigned short)(q3 >> 16)),     ay1);
  }
  for (; e < e1; ++e){
    int c = cols[e];
    float v = ldf(vals, e, fl);
    unsigned int q = *(const unsigned int*)&Y[(long)c * 128 + 2 * lane];
    ax0 = fmaf(v, bf2f((unsigned short)(q & 0xffffu)), ax0);
    ay0 = fmaf(v, bf2f((unsigned short)(q >> 16)),     ay0);
  }
  outx = ax0 + ax1;
  outy = ay0 + ay1;
}

// ---- spmm1 fused: x1[r] = relu(spmm(y1)[r] + b1) + z[r], bf16 out ----
__global__ __launch_bounds__(256) void spmm1_f(
    const int* __restrict__ rs, const int* __restrict__ cols,
    const void* __restrict__ vals, const unsigned short* __restrict__ Y,
    const unsigned short* __restrict__ z, const void* __restrict__ b1,
    unsigned short* __restrict__ x1, int N, const int* __restrict__ flagp)
{
  const int fl   = *flagp;
  const int lane = threadIdx.x & 63;
  const int wav  = threadIdx.x >> 6;
  int r = blockIdx.x * 4 + wav;
  if (r >= N) return;
  int e0 = __builtin_amdgcn_readfirstlane(rs[r]);
  int e1 = __builtin_amdgcn_readfirstlane(rs[r + 1]);
  float ax, ay;
  row_gather(e0, e1, cols, vals, Y, lane, fl, ax, ay);
  long o = (long)r * 128 + 2 * lane;
  float b0 = ldf(b1, 2 * lane, fl), b1v = ldf(b1, 2 * lane + 1, fl);
  unsigned int zz = *(const unsigned int*)&z[o];
  float r0 = fmaxf(ax + b0,  0.f) + bf2f((unsigned short)(zz & 0xffffu));
  float r1 = fmaxf(ay + b1v, 0.f) + bf2f((unsigned short)(zz >> 16));
  *(unsigned int*)&x1[o] = (unsigned int)f2bf(r0) | ((unsigned int)f2bf(r1) << 16);
}

// ---- spmm2 fused: out[r] = log_softmax(spmm(y2)[r] + b2), dtype per flag ----
__global__ __launch_bounds__(256) void spmm2_f(
    const int* __restrict__ rs, const int* __restrict__ cols,
    const void* __restrict__ vals, const unsigned short* __restrict__ Y,
    const void* __restrict__ b2, void* __restrict__ out, int N,
    const int* __restrict__ flagp)
{
  const int fl   = *flagp;
  const int lane = threadIdx.x & 63;
  const int wav  = threadIdx.x >> 6;
  int r = blockIdx.x * 4 + wav;
  if (r >= N) return;
  int e0 = __builtin_amdgcn_readfirstlane(rs[r]);
  int e1 = __builtin_amdgcn_readfirstlane(rs[r + 1]);
  float ax, ay;
  row_gather(e0, e1, cols, vals, Y, lane, fl, ax, ay);
  float v0 = ax + ldf(b2, 2 * lane, fl);
  float v1 = ay + ldf(b2, 2 * lane + 1, fl);
  float m = fmaxf(v0, v1);
#pragma unroll
  for (int off = 32; off; off >>= 1) m = fmaxf(m, __shfl_xor(m, off));
  float s = expf(v0 - m) + expf(v1 - m);
#pragma unroll
  for (int off = 32; off; off >>= 1) s += __shfl_xor(s, off);
  float lse = m + logf(s);
  long o = (long)r * 128 + 2 * lane;
  if (fl){
    float2 w; w.x = v0 - lse; w.y = v1 - lse;
    *(float2*)&((float*)out)[o] = w;
  } else {
    *(unsigned int*)&((unsigned short*)out)[o] =
        (unsigned int)f2bf(v0 - lse) | ((unsigned int)f2bf(v1 - lse) << 16);
  }
}

extern "C" void kernel_launch(void* const* d_in, const int* in_sizes, int n_in,
                              void* d_out, int out_size, void* d_ws, size_t ws_size,
                              hipStream_t stream)
{
  const void* x    = d_in[0];
  const int*  erow = (const int*)d_in[1];
  const int*  ecol = (const int*)d_in[2];
  const void* eval = d_in[3];
  const void* Wres = d_in[4];
  const void* bres = d_in[5];
  const void* W1   = d_in[6];
  const void* b1   = d_in[7];
  const void* W2   = d_in[8];
  const void* b2   = d_in[9];
  const int N = in_sizes[0] / 256;   // 100000
  const int E = in_sizes[1];         // 1600000

  char* ws = (char*)d_ws;
  size_t szB = (size_t)N * 128 * 2;  // one bf16 [N,128] plane (25.6 MB)
  unsigned short* bufA  = (unsigned short*)ws;            // y1, then y2
  unsigned short* bufC  = (unsigned short*)(ws + szB);    // x1
  unsigned short* WresT = (unsigned short*)(ws + 2 * szB);
  unsigned short* W1T   = WresT + 256 * 128;
  unsigned short* W2T   = W1T   + 256 * 128;
  int*            flag  = (int*)(W2T + 256 * 128);
  int*            rs    = flag + 4;                        // [N+1] row_ptr
  unsigned short* zbuf  = (unsigned short*)d_out;          // z (bf16) in d_out

  detect<<<1, 256, 0, stream>>>((const unsigned short*)x, flag);
  wtrans<<<128, 256, 0, stream>>>(Wres, WresT, 256, flag);
  wtrans<<<128, 256, 0, stream>>>(W1,   W1T,   256, flag);
  wtrans<<< 64, 256, 0, stream>>>(W2,   W2T,   128, flag);
  rowptr_k<<<(E + 255) / 256, 256, 0, stream>>>(erow, rs, E, N);

  const int gBlocks = (N + 127) / 128;
  const int rBlocks = (N + 3) / 4;

  gemm_bf16<256><<<gBlocks, 256, 0, stream>>>(x, WresT, bres, zbuf, N, flag, 1);  // z
  gemm_bf16<256><<<gBlocks, 256, 0, stream>>>(x, W1T, nullptr, bufA, N, flag, 1); // y1

  spmm1_f<<<rBlocks, 256, 0, stream>>>(rs, ecol, eval, bufA, zbuf, b1, bufC, N, flag); // x1

  gemm_bf16<128><<<gBlocks, 256, 0, stream>>>(bufC, W2T, nullptr, bufA, N, flag, 0);   // y2

  spmm2_f<<<rBlocks, 256, 0, stream>>>(rs, ecol, eval, bufA, b2, d_out, N, flag);      // out
}